// Round 7
// baseline (153.107 us; speedup 1.0000x reference)
//
#include <hip/hip_runtime.h>

// KANConv2d, round 7: 2 async blocks/CU + reg-staged A (ds_write, no LDS-DMA).
// out[b,o,h,w] = sum_{c,tap,j} Wc[o,c,tap,j] * f_j(xp[b,c,h+dh,w+dw])
// f = {silu(v), B_0..B_6(v)} cardinal cubic B-splines (t = 2v+5), 8 bf16/granule.
// Structure: grid 512 (16b x 32 h-pairs), 256 thr = 4 waves (2 ohalf x 2 hrow),
//   wave = 64o x 64w x 1h (2x2 frags — optimal read:MFMA ratio at this grid).
//   A (weights) reg-staged then ds_write'd, double-buffered per 3-tap substep.
//   B (features) computed in-kernel, single-buffered per cb (4 rows incl. halo).
//   2 blocks/CU: when one block barriers/FEATWs, the other fills the pipes.

#define BB 16
#define CC 64
#define HH 64
#define WW 64
#define OO 128

typedef __bf16 bf16x8 __attribute__((ext_vector_type(8)));
typedef float f32x16 __attribute__((ext_vector_type(16)));

__device__ __forceinline__ bf16x8 as_bf16x8(uint4 v) { return __builtin_bit_cast(bf16x8, v); }
__device__ __forceinline__ unsigned bfb(float f) {
    return (unsigned)__builtin_bit_cast(unsigned short, (__bf16)f);
}

// 8-feature granule {silu(v), B_0(v)..B_6(v)} packed as 8 bf16 via 128-bit shift scatter.
__device__ __forceinline__ uint4 feat_granule(float v) {
    const float silu = __fdividef(v, 1.f + __expf(-v));
    const float t  = fmaf(2.f, v, 5.f);
    const float fi = floorf(t);
    const float u  = t - fi;
    const float um = 1.f - u;
    const float u2 = u * u, u3 = u2 * u;
    const float k0 = um * um * um * (1.f / 6.f);
    const float k1 = fmaf(0.5f, u3, (2.f / 3.f) - u2);
    const float k2 = fmaf(-0.5f, u3, fmaf(0.5f, u2, fmaf(0.5f, u, 1.f / 6.f)));
    const float k3 = u3 * (1.f / 6.f);
    const bool valid = (t >= 0.f) && (t < 10.f);
    unsigned long long K =
        (unsigned long long)bfb(k0)         |
        ((unsigned long long)bfb(k1) << 16) |
        ((unsigned long long)bfb(k2) << 32) |
        ((unsigned long long)bfb(k3) << 48);
    if (!valid) K = 0ull;
    const int ic = min(max((int)fi, -2), 9);
    const int sh = 16 * ic - 32;            // [-64, 112]
    unsigned __int128 P = (sh >= 0) ? ((unsigned __int128)K << sh)
                                    : ((unsigned __int128)K >> (-sh));
    uint4 pk = __builtin_bit_cast(uint4, P);
    pk.x = (pk.x & 0xFFFF0000u) | bfb(silu);
    return pk;
}

// ---------------- weight prep: Wb[cb][tap][c_l][o][j] bf16, j contiguous ----------------
__global__ __launch_bounds__(256) void kan_wprep(
    const float* __restrict__ beta, const float* __restrict__ spl,
    const float* __restrict__ cf, uint4* __restrict__ wb)
{
    int t = blockIdx.x * 256 + threadIdx.x;      // 73728 = (o, c, tap)
    int tap = t % 9;
    int c   = (t / 9) & 63;
    int o   = t / 576;
    int base = (o * CC + c) * 9 + tap;
    float bv = beta[base];
    float sv = spl[base];
    float f[8];
    f[0] = bv;
    #pragma unroll
    for (int s = 0; s < 7; ++s)
        f[1 + s] = sv * cf[((s * OO + o) * CC + c) * 9 + tap];
    uint4 pk;
    pk.x = bfb(f[0]) | (bfb(f[1]) << 16);
    pk.y = bfb(f[2]) | (bfb(f[3]) << 16);
    pk.z = bfb(f[4]) | (bfb(f[5]) << 16);
    pk.w = bfb(f[6]) | (bfb(f[7]) << 16);
    int cb = c >> 2, cl = c & 3;
    wb[((cb * 9 + tap) * 4 + cl) * OO + o] = pk;
}

// ---------------- main implicit GEMM ----------------
__global__ __launch_bounds__(256, 2) void kan_mfma4(
    const float* __restrict__ x, const uint4* __restrict__ wb,
    float* __restrict__ out)
{
    // B/features: [cl][row 0..3][col 0..65], single buffer per cb
    __shared__ uint4 Bt[1056];
    // A/weights substep tile: [buf][(tl*4 + cl)*128 + o]
    __shared__ uint4 At[2][1536];

    const int tid = threadIdx.x;
    const int blk = blockIdx.x;
    const int hp2 = blk & 31;
    const int b   = blk >> 5;
    const int h0  = hp2 << 1;          // output rows h0, h0+1; input rows h0-1..h0+2

    const int ww    = tid >> 6;        // wave 0..3
    const int lane  = tid & 63;
    const int lo    = lane & 31;
    const int hi    = lane >> 5;
    const int ohalf = ww & 1;
    const int hrow  = ww >> 1;         // 0..1

    f32x16 acc[2][2] = {};             // [oi][wi]
    float xv[5];
    uint4 aw[6];

    // ---- x loads for channel-block cbi: 1056 granule-pixels (4 cl x 4 rows x 66) ----
    #define XLOAD(cbi) do {                                                   \
        _Pragma("unroll")                                                     \
        for (int k = 0; k < 5; ++k) {                                         \
            const int g = tid + k * 256;                                      \
            float v = 0.f;                                                    \
            if (g < 1056) {                                                   \
                const int cl_ = g / 264;                                      \
                const int r_  = (g % 264) / 66;                               \
                const int co_ = g % 66;                                       \
                const int hx  = h0 - 1 + r_;                                  \
                const int wx  = co_ - 1;                                      \
                if ((unsigned)hx < 64u && (unsigned)wx < 64u)                 \
                    v = x[((b * CC + (cbi) * 4 + cl_) * HH + hx) * WW + wx];  \
            }                                                                 \
            xv[k] = v;                                                        \
        }                                                                     \
    } while (0)

    // ---- feature compute + LDS write into Bt ----
    #define FEATW() do {                                                      \
        _Pragma("unroll")                                                     \
        for (int k = 0; k < 5; ++k) {                                         \
            const int g = tid + k * 256;                                      \
            if (g < 1056) Bt[g] = feat_granule(xv[k]);                        \
        }                                                                     \
    } while (0)

    // ---- A substep (cb1, dh1): global -> regs (issue early) ----
    #define ALOAD(cb1, dh1) do {                                              \
        const uint4* asrc = wb + ((cb1) * 4608 + (dh1) * 1536)                \
                            + ww * 384 + lane;                                \
        _Pragma("unroll")                                                     \
        for (int i = 0; i < 6; ++i) aw[i] = asrc[i * 64];                     \
    } while (0)

    // ---- regs -> LDS (write late, after MFMAs) ----
    #define AWRITE(bufi) do {                                                 \
        _Pragma("unroll")                                                     \
        for (int i = 0; i < 6; ++i)                                           \
            At[bufi][ww * 384 + i * 64 + lane] = aw[i];                       \
    } while (0)

    // prologue: features + A substep 0
    XLOAD(0);
    ALOAD(0, 0);
    FEATW();
    AWRITE(0);
    __syncthreads();

    #pragma unroll 1
    for (int cb = 0; cb < 16; ++cb) {
        #pragma unroll
        for (int dh = 0; dh < 3; ++dh) {
            const int s   = cb * 3 + dh;
            const int buf = s & 1;

            if (s < 47) {                        // issue next A substep early
                const int cb1 = (dh == 2) ? cb + 1 : cb;
                const int dh1 = (dh == 2) ? 0 : dh + 1;
                ALOAD(cb1, dh1);
            }
            if (dh == 0 && cb < 15) XLOAD(cb + 1);   // issue next x early

            const uint4* Ab = At[buf];
            #pragma unroll
            for (int tl = 0; tl < 3; ++tl) {         // tap = dh*3+tl, dw = tl
                bf16x8 Af[2][2], Bf[2][2];           // [kh][oi] / [kh][wi]
                #pragma unroll
                for (int kh = 0; kh < 2; ++kh) {
                    const int arow = (tl * 4 + kh * 2 + hi) * 128 + ohalf * 64 + lo;
                    Af[kh][0] = as_bf16x8(Ab[arow]);
                    Af[kh][1] = as_bf16x8(Ab[arow + 32]);
                    const int brow = ((kh * 2 + hi) * 4 + hrow + dh) * 66 + tl + lo;
                    Bf[kh][0] = as_bf16x8(Bt[brow]);
                    Bf[kh][1] = as_bf16x8(Bt[brow + 32]);
                }
                __builtin_amdgcn_s_setprio(1);
                #pragma unroll
                for (int oi = 0; oi < 2; ++oi)
                    #pragma unroll
                    for (int wi = 0; wi < 2; ++wi)
                        #pragma unroll
                        for (int kh = 0; kh < 2; ++kh)
                            acc[oi][wi] = __builtin_amdgcn_mfma_f32_32x32x16_bf16(
                                Af[kh][oi], Bf[kh][wi], acc[oi][wi], 0, 0, 0);
                __builtin_amdgcn_s_setprio(0);
            }

            if (s < 47) AWRITE(buf ^ 1);             // write-late (T14)

            if (dh == 2 && cb < 15) {
                __syncthreads();                     // all reads of Bt[cb] done
                FEATW();                             // overwrite with cb+1 features
            }
            __syncthreads();                         // At[buf^1] (+Bt) visible
        }
    }

    // ---- store: w-coalesced dword stores ----
    const int h = h0 + hrow;
    #pragma unroll
    for (int oi = 0; oi < 2; ++oi)
        #pragma unroll
        for (int wi = 0; wi < 2; ++wi) {
            const int wc = wi * 32 + lo;
            #pragma unroll
            for (int r = 0; r < 16; ++r) {
                const int o = ohalf * 64 + oi * 32 + (r & 3) + ((r >> 2) << 3) + (hi << 2);
                out[((b * OO + o) * HH + h) * WW + wc] = acc[oi][wi][r];
            }
        }
}

extern "C" void kernel_launch(void* const* d_in, const int* in_sizes, int n_in,
                              void* d_out, int out_size, void* d_ws, size_t ws_size,
                              hipStream_t stream) {
    const float* x    = (const float*)d_in[0];
    const float* beta = (const float*)d_in[1];
    const float* spl  = (const float*)d_in[2];
    const float* cf   = (const float*)d_in[3];
    float* out = (float*)d_out;
    uint4* wb  = (uint4*)d_ws;          // 73728 granules = 1.18 MB

    kan_wprep<<<288, 256, 0, stream>>>(beta, spl, cf, wb);
    kan_mfma4<<<BB * 32, 256, 0, stream>>>(x, wb, out);
}

// Round 8
// 108.058 us; speedup vs baseline: 1.4169x; 1.4169x over previous
//
#include <hip/hip_runtime.h>

// KANConv2d, round 8: R6 geometry + register-pipelined A staging (no LDS-DMA).
// out[b,o,h,w] = sum_{c,tap,j} Wc[o,c,tap,j] * f_j(xp[b,c,h+dh,w+dw])
// f = {silu(v), B_0..B_6(v)} cardinal cubic B-splines (t = 2v+5), 8 bf16/granule.
// Structure: grid 256 (b x hquad), 1 block/CU, 8 waves (wave = 64o x 64w x 1h, 2x2 frags).
//   A (weights): global->VGPR issued one substep ahead (dh-indexed reg sets rA/rB/rC,
//   compile-time selection), ds_write_b128 into double-buffered At after the MFMAs.
//   Loads ride across barriers (no global_load_lds -> no vmcnt(0) barrier drain).
//   B (features): computed in-kernel, double-buffered per cb. All LDS reads conflict-free.

#define BB 16
#define CC 64
#define HH 64
#define WW 64
#define OO 128

typedef __bf16 bf16x8 __attribute__((ext_vector_type(8)));
typedef float f32x16 __attribute__((ext_vector_type(16)));

__device__ __forceinline__ bf16x8 as_bf16x8(uint4 v) { return __builtin_bit_cast(bf16x8, v); }
__device__ __forceinline__ unsigned bfb(float f) {
    return (unsigned)__builtin_bit_cast(unsigned short, (__bf16)f);
}

// 8-feature granule {silu(v), B_0(v)..B_6(v)} packed as 8 bf16 via 128-bit shift scatter.
__device__ __forceinline__ uint4 feat_granule(float v) {
    const float silu = __fdividef(v, 1.f + __expf(-v));
    const float t  = fmaf(2.f, v, 5.f);
    const float fi = floorf(t);
    const float u  = t - fi;
    const float um = 1.f - u;
    const float u2 = u * u, u3 = u2 * u;
    const float k0 = um * um * um * (1.f / 6.f);
    const float k1 = fmaf(0.5f, u3, (2.f / 3.f) - u2);
    const float k2 = fmaf(-0.5f, u3, fmaf(0.5f, u2, fmaf(0.5f, u, 1.f / 6.f)));
    const float k3 = u3 * (1.f / 6.f);
    const bool valid = (t >= 0.f) && (t < 10.f);
    unsigned long long K =
        (unsigned long long)bfb(k0)         |
        ((unsigned long long)bfb(k1) << 16) |
        ((unsigned long long)bfb(k2) << 32) |
        ((unsigned long long)bfb(k3) << 48);
    if (!valid) K = 0ull;
    const int ic = min(max((int)fi, -2), 9);
    const int sh = 16 * ic - 32;            // [-64, 112]
    unsigned __int128 P = (sh >= 0) ? ((unsigned __int128)K << sh)
                                    : ((unsigned __int128)K >> (-sh));
    uint4 pk = __builtin_bit_cast(uint4, P);
    pk.x = (pk.x & 0xFFFF0000u) | bfb(silu);
    return pk;
}

// ---------------- weight prep: Wb[cb][tap][c_l][o][j] bf16, j contiguous ----------------
__global__ __launch_bounds__(256) void kan_wprep(
    const float* __restrict__ beta, const float* __restrict__ spl,
    const float* __restrict__ cf, uint4* __restrict__ wb)
{
    int t = blockIdx.x * 256 + threadIdx.x;      // 73728 = (o, c, tap)
    int tap = t % 9;
    int c   = (t / 9) & 63;
    int o   = t / 576;
    int base = (o * CC + c) * 9 + tap;
    float bv = beta[base];
    float sv = spl[base];
    float f[8];
    f[0] = bv;
    #pragma unroll
    for (int s = 0; s < 7; ++s)
        f[1 + s] = sv * cf[((s * OO + o) * CC + c) * 9 + tap];
    uint4 pk;
    pk.x = bfb(f[0]) | (bfb(f[1]) << 16);
    pk.y = bfb(f[2]) | (bfb(f[3]) << 16);
    pk.z = bfb(f[4]) | (bfb(f[5]) << 16);
    pk.w = bfb(f[6]) | (bfb(f[7]) << 16);
    int cb = c >> 2, cl = c & 3;
    wb[((cb * 9 + tap) * 4 + cl) * OO + o] = pk;
}

// ---------------- main implicit GEMM ----------------
__global__ __launch_bounds__(512, 2) void kan_mfma5(
    const float* __restrict__ x, const uint4* __restrict__ wb,
    float* __restrict__ out)
{
    // B/features: [buf][(cl*6 + row)*66 + col], 1584 granules/buf
    __shared__ uint4 Bt[2][1584];
    // A/weights substep tile: [buf][(tl*4 + cl)*128 + o], 1536 granules/buf
    __shared__ uint4 At[2][1536];

    const int tid  = threadIdx.x;
    const int blk  = blockIdx.x;
    const int hq   = blk & 15;
    const int b    = blk >> 4;
    const int h0   = hq << 2;          // output rows h0..h0+3; input rows h0-1..h0+4

    const int ww    = tid >> 6;        // wave 0..7
    const int lane  = tid & 63;
    const int lo    = lane & 31;
    const int hi    = lane >> 5;
    const int ohalf = ww & 1;
    const int hrow  = ww >> 1;         // 0..3

    f32x16 acc[2][2] = {};             // [oi][wi]
    float xv[4];
    uint4 rA[3], rB[3], rC[3];         // dh-indexed A reg pipeline (compile-time sel)

    // ---- x loads for channel-block cbi: 1584 granule-pixels (4cl x 6rows x 66) ----
    #define XLOAD(cbi) do {                                                   \
        _Pragma("unroll")                                                     \
        for (int k = 0; k < 4; ++k) {                                         \
            const int g = tid + k * 512;                                      \
            float v = 0.f;                                                    \
            if (g < 1584) {                                                   \
                const int cl_ = g / 396;                                      \
                const int r_  = (g % 396) / 66;                               \
                const int co_ = g % 66;                                       \
                const int hx  = h0 - 1 + r_;                                  \
                const int wx  = co_ - 1;                                      \
                if ((unsigned)hx < 64u && (unsigned)wx < 64u)                 \
                    v = x[((b * CC + (cbi) * 4 + cl_) * HH + hx) * WW + wx];  \
            }                                                                 \
            xv[k] = v;                                                        \
        }                                                                     \
    } while (0)

    // ---- feature compute + LDS write into Bt[bufi] ----
    #define FEATW(bufi) do {                                                  \
        _Pragma("unroll")                                                     \
        for (int k = 0; k < 4; ++k) {                                         \
            const int g = tid + k * 512;                                      \
            if (g < 1584) Bt[bufi][g] = feat_granule(xv[k]);                  \
        }                                                                     \
    } while (0)

    // ---- A substep (cb1, dh1): global -> regs (issue early, consumed next substep) ----
    #define ALOADR(regs, cb1, dh1) do {                                       \
        const uint4* asrc = wb + (cb1) * 4608 + (dh1) * 1536 + tid;           \
        _Pragma("unroll")                                                     \
        for (int i = 0; i < 3; ++i) regs[i] = asrc[i * 512];                  \
    } while (0)

    // ---- regs -> LDS (write late, after MFMAs) ----
    #define AWRITER(regs, bufi) do {                                          \
        _Pragma("unroll")                                                     \
        for (int i = 0; i < 3; ++i) At[bufi][tid + i * 512] = regs[i];        \
    } while (0)

    // prologue: Bt[0] <- features(cb0); At[0] <- A(0,0); rC <- A(0,1)
    XLOAD(0);
    ALOADR(rC, 0, 0);
    FEATW(0);
    AWRITER(rC, 0);
    ALOADR(rC, 0, 1);
    __syncthreads();

    #pragma unroll 1
    for (int cb = 0; cb < 16; ++cb) {
        #pragma unroll
        for (int dh = 0; dh < 3; ++dh) {
            // substep s = cb*3+dh reads At[(cb+dh)&1], Bt[cb&1]
            if (dh == 0 && cb < 15) XLOAD(cb + 1);

            // issue A loads for substep s+2 (consumed by AWRITER at s+1)
            if (dh == 0)               ALOADR(rA, cb, 2);
            else if (dh == 1) { if (cb < 15) ALOADR(rB, cb + 1, 0); }
            else              { if (cb < 15) ALOADR(rC, cb + 1, 1); }

            const uint4* Ab = At[(cb + dh) & 1];
            const uint4* Bb = Bt[cb & 1];

            #pragma unroll
            for (int tl = 0; tl < 3; ++tl) {         // tap = dh*3+tl, dw = tl
                bf16x8 Af[2][2], Bf[2][2];           // [kh][oi] / [kh][wi]
                #pragma unroll
                for (int kh = 0; kh < 2; ++kh) {
                    const int arow = (tl * 4 + kh * 2 + hi) * 128 + ohalf * 64 + lo;
                    Af[kh][0] = as_bf16x8(Ab[arow]);
                    Af[kh][1] = as_bf16x8(Ab[arow + 32]);
                    const int brow = ((kh * 2 + hi) * 6 + hrow + dh) * 66 + tl + lo;
                    Bf[kh][0] = as_bf16x8(Bb[brow]);
                    Bf[kh][1] = as_bf16x8(Bb[brow + 32]);
                }
                __builtin_amdgcn_s_setprio(1);
                #pragma unroll
                for (int oi = 0; oi < 2; ++oi)
                    #pragma unroll
                    for (int wi = 0; wi < 2; ++wi)
                        #pragma unroll
                        for (int kh = 0; kh < 2; ++kh)
                            acc[oi][wi] = __builtin_amdgcn_mfma_f32_32x32x16_bf16(
                                Af[kh][oi], Bf[kh][wi], acc[oi][wi], 0, 0, 0);
                __builtin_amdgcn_s_setprio(0);
            }

            // write A for substep s+1 into At[(cb+dh+1)&1]; regs loaded 1 substep ago
            if (dh == 0)               AWRITER(rC, (cb + 1) & 1);  // A(cb,1)
            else if (dh == 1)          AWRITER(rA, cb & 1);        // A(cb,2)
            else { if (cb < 15)        AWRITER(rB, (cb + 1) & 1); }// A(cb+1,0)

            if (dh == 2 && cb < 15) FEATW((cb + 1) & 1);   // write-late features

            __syncthreads();
        }
    }

    // ---- store: w-coalesced dword stores ----
    const int h = h0 + hrow;
    #pragma unroll
    for (int oi = 0; oi < 2; ++oi)
        #pragma unroll
        for (int wi = 0; wi < 2; ++wi) {
            const int wc = wi * 32 + lo;
            #pragma unroll
            for (int r = 0; r < 16; ++r) {
                const int o = ohalf * 64 + oi * 32 + (r & 3) + ((r >> 2) << 3) + (hi << 2);
                out[((b * OO + o) * HH + h) * WW + wc] = acc[oi][wi][r];
            }
        }
}

extern "C" void kernel_launch(void* const* d_in, const int* in_sizes, int n_in,
                              void* d_out, int out_size, void* d_ws, size_t ws_size,
                              hipStream_t stream) {
    const float* x    = (const float*)d_in[0];
    const float* beta = (const float*)d_in[1];
    const float* spl  = (const float*)d_in[2];
    const float* cf   = (const float*)d_in[3];
    float* out = (float*)d_out;
    uint4* wb  = (uint4*)d_ws;          // 73728 granules = 1.18 MB

    kan_wprep<<<288, 256, 0, stream>>>(beta, spl, cf, wb);
    kan_mfma5<<<BB * 16, 512, 0, stream>>>(x, wb, out);
}

// Round 9
// 101.887 us; speedup vs baseline: 1.5027x; 1.0606x over previous
//
#include <hip/hip_runtime.h>

// KANConv2d, round 9: R6 structure with 4x2 fragment tile (LDS-read-balanced).
// out[b,o,h,w] = sum_{c,tap,j} Wc[o,c,tap,j] * f_j(xp[b,c,h+dh,w+dw])
// f = {silu(v), B_0..B_6(v)} cardinal cubic B-splines (t = 2v+5), 8 bf16/granule.
// Structure: grid 256 (b x hquad), 1 block/CU, 4 waves; wave = 128o x 64w x 1h
//   (4 oi x 2 wi frags -> 0.75 ds_read_b128 per MFMA; LDS-port ~ MFMA balanced).
//   A (weights) DMA'd to LDS (global_load_lds w16), double-buffered per 3-tap substep.
//   B (features) computed in-kernel, double-buffered per channel-block.
//   All LDS reads lane-consecutive 16B granules (conflict-free, verified R6).

#define BB 16
#define CC 64
#define HH 64
#define WW 64
#define OO 128

typedef __bf16 bf16x8 __attribute__((ext_vector_type(8)));
typedef float f32x16 __attribute__((ext_vector_type(16)));

__device__ __forceinline__ bf16x8 as_bf16x8(uint4 v) { return __builtin_bit_cast(bf16x8, v); }
__device__ __forceinline__ unsigned bfb(float f) {
    return (unsigned)__builtin_bit_cast(unsigned short, (__bf16)f);
}

// 8-feature granule {silu(v), B_0(v)..B_6(v)} packed as 8 bf16 via 128-bit shift scatter.
__device__ __forceinline__ uint4 feat_granule(float v) {
    const float silu = __fdividef(v, 1.f + __expf(-v));
    const float t  = fmaf(2.f, v, 5.f);
    const float fi = floorf(t);
    const float u  = t - fi;
    const float um = 1.f - u;
    const float u2 = u * u, u3 = u2 * u;
    const float k0 = um * um * um * (1.f / 6.f);
    const float k1 = fmaf(0.5f, u3, (2.f / 3.f) - u2);
    const float k2 = fmaf(-0.5f, u3, fmaf(0.5f, u2, fmaf(0.5f, u, 1.f / 6.f)));
    const float k3 = u3 * (1.f / 6.f);
    const bool valid = (t >= 0.f) && (t < 10.f);
    unsigned long long K =
        (unsigned long long)bfb(k0)         |
        ((unsigned long long)bfb(k1) << 16) |
        ((unsigned long long)bfb(k2) << 32) |
        ((unsigned long long)bfb(k3) << 48);
    if (!valid) K = 0ull;
    const int ic = min(max((int)fi, -2), 9);
    const int sh = 16 * ic - 32;            // [-64, 112]
    unsigned __int128 P = (sh >= 0) ? ((unsigned __int128)K << sh)
                                    : ((unsigned __int128)K >> (-sh));
    uint4 pk = __builtin_bit_cast(uint4, P);
    pk.x = (pk.x & 0xFFFF0000u) | bfb(silu);
    return pk;
}

// ---------------- weight prep: Wb[cb][tap][c_l][o][j] bf16, j contiguous ----------------
__global__ __launch_bounds__(256) void kan_wprep(
    const float* __restrict__ beta, const float* __restrict__ spl,
    const float* __restrict__ cf, uint4* __restrict__ wb)
{
    int t = blockIdx.x * 256 + threadIdx.x;      // 73728 = (o, c, tap)
    int tap = t % 9;
    int c   = (t / 9) & 63;
    int o   = t / 576;
    int base = (o * CC + c) * 9 + tap;
    float bv = beta[base];
    float sv = spl[base];
    float f[8];
    f[0] = bv;
    #pragma unroll
    for (int s = 0; s < 7; ++s)
        f[1 + s] = sv * cf[((s * OO + o) * CC + c) * 9 + tap];
    uint4 pk;
    pk.x = bfb(f[0]) | (bfb(f[1]) << 16);
    pk.y = bfb(f[2]) | (bfb(f[3]) << 16);
    pk.z = bfb(f[4]) | (bfb(f[5]) << 16);
    pk.w = bfb(f[6]) | (bfb(f[7]) << 16);
    int cb = c >> 2, cl = c & 3;
    wb[((cb * 9 + tap) * 4 + cl) * OO + o] = pk;
}

// ---------------- main implicit GEMM ----------------
__global__ __launch_bounds__(256, 1) void kan_mfma6(
    const float* __restrict__ x, const uint4* __restrict__ wb,
    float* __restrict__ out)
{
    // B/features: [buf][(cl*6 + row)*66 + col], 1584 granules/buf
    __shared__ uint4 Bt[2][1584];
    // A/weights substep tile: [buf][(tl*4 + cl)*128 + o], 1536 granules/buf
    __shared__ uint4 At[2][1536];

    const int tid  = threadIdx.x;
    const int blk  = blockIdx.x;
    const int hq   = blk & 15;
    const int b    = blk >> 4;
    const int h0   = hq << 2;          // output rows h0..h0+3; input rows h0-1..h0+4

    const int ww    = tid >> 6;        // wave 0..3 = output row
    const int lane  = tid & 63;
    const int lo    = lane & 31;
    const int hi    = lane >> 5;
    const int hrow  = ww;

    f32x16 acc[4][2] = {};             // [oi][wi]
    float xv[7];

    // ---- x loads for channel-block cbi: 1584 granule-pixels (4cl x 6rows x 66) ----
    #define XLOAD(cbi) do {                                                   \
        _Pragma("unroll")                                                     \
        for (int k = 0; k < 7; ++k) {                                         \
            const int g = tid + k * 256;                                      \
            float v = 0.f;                                                    \
            if (g < 1584) {                                                   \
                const int cl_ = g / 396;                                      \
                const int r_  = (g % 396) / 66;                               \
                const int co_ = g % 66;                                       \
                const int hx  = h0 - 1 + r_;                                  \
                const int wx  = co_ - 1;                                      \
                if ((unsigned)hx < 64u && (unsigned)wx < 64u)                 \
                    v = x[((b * CC + (cbi) * 4 + cl_) * HH + hx) * WW + wx];  \
            }                                                                 \
            xv[k] = v;                                                        \
        }                                                                     \
    } while (0)

    // ---- feature compute + LDS write into Bt[bufi] ----
    #define FEATW(bufi) do {                                                  \
        _Pragma("unroll")                                                     \
        for (int k = 0; k < 7; ++k) {                                         \
            const int g = tid + k * 256;                                      \
            if (g < 1584) Bt[bufi][g] = feat_granule(xv[k]);                  \
        }                                                                     \
    } while (0)

    // ---- DMA one A substep slice (cb1, dh1) into At[bufi]: 6 chunks/wave ----
    #define ADMA(bufi, cb1, dh1) do {                                         \
        const uint4* asrc = wb + ((cb1) * 4608 + (dh1) * 1536)                \
                            + ww * 384 + lane;                                \
        _Pragma("unroll")                                                     \
        for (int i = 0; i < 6; ++i)                                           \
            __builtin_amdgcn_global_load_lds(                                 \
                (const __attribute__((address_space(1))) void*)(asrc + i*64), \
                (__attribute__((address_space(3))) void*)                     \
                    &At[bufi][ww * 384 + i * 64],                             \
                16, 0, 0);                                                    \
    } while (0)

    // prologue: x + features for cb=0, A substep 0
    XLOAD(0);
    ADMA(0, 0, 0);
    FEATW(0);
    __syncthreads();

    #pragma unroll 1
    for (int cb = 0; cb < 16; ++cb) {
        const int bbuf = cb & 1;

        #pragma unroll
        for (int dh = 0; dh < 3; ++dh) {
            const int buf = (cb + dh) & 1;       // s = cb*3+dh; s&1 == (cb+dh)&1

            // stage next A substep (lands during this substep's MFMAs)
            if (cb < 15 || dh < 2) {
                const int cb1 = (dh == 2) ? cb + 1 : cb;
                const int dh1 = (dh == 2) ? 0 : dh + 1;
                ADMA(buf ^ 1, cb1, dh1);
            }
            if (dh == 0 && cb < 15) XLOAD(cb + 1);   // issue-early (T14)

            const uint4* Ab = At[buf];
            const uint4* Bb = Bt[bbuf];
            #pragma unroll
            for (int tl = 0; tl < 3; ++tl) {         // tap = dh*3+tl, dw = tl
                bf16x8 Af[2][4], Bf[2][2];           // [kh][oi] / [kh][wi]
                #pragma unroll
                for (int kh = 0; kh < 2; ++kh) {
                    const int arow = (tl * 4 + kh * 2 + hi) * 128 + lo;
                    #pragma unroll
                    for (int oi = 0; oi < 4; ++oi)
                        Af[kh][oi] = as_bf16x8(Ab[arow + oi * 32]);
                    const int brow = ((kh * 2 + hi) * 6 + hrow + dh) * 66 + tl + lo;
                    Bf[kh][0] = as_bf16x8(Bb[brow]);
                    Bf[kh][1] = as_bf16x8(Bb[brow + 32]);
                }
                __builtin_amdgcn_s_setprio(1);
                #pragma unroll
                for (int oi = 0; oi < 4; ++oi)
                    #pragma unroll
                    for (int wi = 0; wi < 2; ++wi)
                        #pragma unroll
                        for (int kh = 0; kh < 2; ++kh)
                            acc[oi][wi] = __builtin_amdgcn_mfma_f32_32x32x16_bf16(
                                Af[kh][oi], Bf[kh][wi], acc[oi][wi], 0, 0, 0);
                __builtin_amdgcn_s_setprio(0);
            }

            if (dh == 2 && cb < 15) FEATW((cb + 1) & 1);  // write-late (T14)
            __syncthreads();
        }
    }

    // ---- store: w-coalesced dword stores ----
    const int h = h0 + hrow;
    #pragma unroll
    for (int oi = 0; oi < 4; ++oi)
        #pragma unroll
        for (int wi = 0; wi < 2; ++wi) {
            const int wc = wi * 32 + lo;
            #pragma unroll
            for (int r = 0; r < 16; ++r) {
                const int o = oi * 32 + (r & 3) + ((r >> 2) << 3) + (hi << 2);
                out[((b * OO + o) * HH + h) * WW + wc] = acc[oi][wi][r];
            }
        }
}

extern "C" void kernel_launch(void* const* d_in, const int* in_sizes, int n_in,
                              void* d_out, int out_size, void* d_ws, size_t ws_size,
                              hipStream_t stream) {
    const float* x    = (const float*)d_in[0];
    const float* beta = (const float*)d_in[1];
    const float* spl  = (const float*)d_in[2];
    const float* cf   = (const float*)d_in[3];
    float* out = (float*)d_out;
    uint4* wb  = (uint4*)d_ws;          // 73728 granules = 1.18 MB

    kan_wprep<<<288, 256, 0, stream>>>(beta, spl, cf, wb);
    kan_mfma6<<<BB * 16, 256, 0, stream>>>(x, wb, out);
}

// Round 10
// 90.887 us; speedup vs baseline: 1.6846x; 1.1210x over previous
//
#include <hip/hip_runtime.h>

// KANConv2d, round 10: R6 structure + counted-vmcnt raw barriers (no per-substep drain).
// out[b,o,h,w] = sum_{c,tap,j} Wc[o,c,tap,j] * f_j(xp[b,c,h+dh,w+dw])
// f = {silu(v), B_0..B_6(v)} cardinal cubic B-splines (t = 2v+5), 8 bf16/granule.
// Structure: grid 256 (b x hquad), 1 block/CU, 8 waves (wave = 64o x 64w x 1h, 2x2 frags).
//   A (weights): global_load_lds DMA, TRIPLE-buffered At[dh], issued 2 substeps ahead;
//     barriers are raw s_barrier with counted s_waitcnt vmcnt(N) (N = vmem ops issued
//     since the DMA that must have landed) -- the DMA rides across barriers (T3/T4).
//   B (features): computed in-kernel, double-buffered per cb; lgkmcnt(0) only at the
//     dh==2 barrier (where FEATW publishes) and prologue.

#define BB 16
#define CC 64
#define HH 64
#define WW 64
#define OO 128

typedef __bf16 bf16x8 __attribute__((ext_vector_type(8)));
typedef float f32x16 __attribute__((ext_vector_type(16)));

__device__ __forceinline__ bf16x8 as_bf16x8(uint4 v) { return __builtin_bit_cast(bf16x8, v); }
__device__ __forceinline__ unsigned bfb(float f) {
    return (unsigned)__builtin_bit_cast(unsigned short, (__bf16)f);
}

// 8-feature granule {silu(v), B_0(v)..B_6(v)} packed as 8 bf16 via 128-bit shift scatter.
__device__ __forceinline__ uint4 feat_granule(float v) {
    const float silu = __fdividef(v, 1.f + __expf(-v));
    const float t  = fmaf(2.f, v, 5.f);
    const float fi = floorf(t);
    const float u  = t - fi;
    const float um = 1.f - u;
    const float u2 = u * u, u3 = u2 * u;
    const float k0 = um * um * um * (1.f / 6.f);
    const float k1 = fmaf(0.5f, u3, (2.f / 3.f) - u2);
    const float k2 = fmaf(-0.5f, u3, fmaf(0.5f, u2, fmaf(0.5f, u, 1.f / 6.f)));
    const float k3 = u3 * (1.f / 6.f);
    const bool valid = (t >= 0.f) && (t < 10.f);
    unsigned long long K =
        (unsigned long long)bfb(k0)         |
        ((unsigned long long)bfb(k1) << 16) |
        ((unsigned long long)bfb(k2) << 32) |
        ((unsigned long long)bfb(k3) << 48);
    if (!valid) K = 0ull;
    const int ic = min(max((int)fi, -2), 9);
    const int sh = 16 * ic - 32;            // [-64, 112]
    unsigned __int128 P = (sh >= 0) ? ((unsigned __int128)K << sh)
                                    : ((unsigned __int128)K >> (-sh));
    uint4 pk = __builtin_bit_cast(uint4, P);
    pk.x = (pk.x & 0xFFFF0000u) | bfb(silu);
    return pk;
}

// ---------------- weight prep: Wb[cb][tap][c_l][o][j] bf16, j contiguous ----------------
__global__ __launch_bounds__(256) void kan_wprep(
    const float* __restrict__ beta, const float* __restrict__ spl,
    const float* __restrict__ cf, uint4* __restrict__ wb)
{
    int t = blockIdx.x * 256 + threadIdx.x;      // 73728 = (o, c, tap)
    int tap = t % 9;
    int c   = (t / 9) & 63;
    int o   = t / 576;
    int base = (o * CC + c) * 9 + tap;
    float bv = beta[base];
    float sv = spl[base];
    float f[8];
    f[0] = bv;
    #pragma unroll
    for (int s = 0; s < 7; ++s)
        f[1 + s] = sv * cf[((s * OO + o) * CC + c) * 9 + tap];
    uint4 pk;
    pk.x = bfb(f[0]) | (bfb(f[1]) << 16);
    pk.y = bfb(f[2]) | (bfb(f[3]) << 16);
    pk.z = bfb(f[4]) | (bfb(f[5]) << 16);
    pk.w = bfb(f[6]) | (bfb(f[7]) << 16);
    int cb = c >> 2, cl = c & 3;
    wb[((cb * 9 + tap) * 4 + cl) * OO + o] = pk;
}

// ---------------- main implicit GEMM ----------------
__global__ __launch_bounds__(512, 2) void kan_mfma7(
    const float* __restrict__ x, const uint4* __restrict__ wb,
    float* __restrict__ out)
{
    // B/features: [buf][(cl*6 + row)*66 + col], 1584 granules/buf
    __shared__ uint4 Bt[2][1584];
    // A/weights substep tile: TRIPLE buffered, At[dh] holds (cb, dh)
    __shared__ uint4 At[3][1536];

    const int tid  = threadIdx.x;
    const int blk  = blockIdx.x;
    const int hq   = blk & 15;
    const int b    = blk >> 4;
    const int h0   = hq << 2;          // output rows h0..h0+3; input rows h0-1..h0+4

    const int ww    = tid >> 6;        // wave 0..7
    const int lane  = tid & 63;
    const int lo    = lane & 31;
    const int hi    = lane >> 5;
    const int ohalf = ww & 1;
    const int hrow  = ww >> 1;         // 0..3

    f32x16 acc[2][2] = {};             // [oi][wi]
    float xv[4];

    // ---- x loads for channel-block cbi: 1584 granule-pixels (4cl x 6rows x 66) ----
    #define XLOAD(cbi) do {                                                   \
        _Pragma("unroll")                                                     \
        for (int k = 0; k < 4; ++k) {                                         \
            const int g = tid + k * 512;                                      \
            float v = 0.f;                                                    \
            if (g < 1584) {                                                   \
                const int cl_ = g / 396;                                      \
                const int r_  = (g % 396) / 66;                               \
                const int co_ = g % 66;                                       \
                const int hx  = h0 - 1 + r_;                                  \
                const int wx  = co_ - 1;                                      \
                if ((unsigned)hx < 64u && (unsigned)wx < 64u)                 \
                    v = x[((b * CC + (cbi) * 4 + cl_) * HH + hx) * WW + wx];  \
            }                                                                 \
            xv[k] = v;                                                        \
        }                                                                     \
    } while (0)

    // ---- feature compute + LDS write into Bt[bufi] ----
    #define FEATW(bufi) do {                                                  \
        _Pragma("unroll")                                                     \
        for (int k = 0; k < 4; ++k) {                                         \
            const int g = tid + k * 512;                                      \
            if (g < 1584) Bt[bufi][g] = feat_granule(xv[k]);                  \
        }                                                                     \
    } while (0)

    // ---- DMA one A substep slice (cb1, dh1) into At[bufi]: 24 x 1KB, 3/wave ----
    #define ADMA(bufi, cb1, dh1) do {                                         \
        const uint4* asrc = wb + ((cb1) * 4608 + (dh1) * 1536)                \
                            + ww * 192 + lane;                                \
        _Pragma("unroll")                                                     \
        for (int i = 0; i < 3; ++i)                                           \
            __builtin_amdgcn_global_load_lds(                                 \
                (const __attribute__((address_space(1))) void*)(asrc + i*64), \
                (__attribute__((address_space(3))) void*)                     \
                    &At[bufi][ww * 192 + i * 64],                             \
                16, 0, 0);                                                    \
    } while (0)

    // prologue: Bt[0] <- features(cb0); At[0] <- (0,0); At[1] <- (0,1); full drain once
    XLOAD(0);
    ADMA(0, 0, 0);
    ADMA(1, 0, 1);
    FEATW(0);
    asm volatile("s_waitcnt vmcnt(0) lgkmcnt(0)" ::: "memory");
    __builtin_amdgcn_s_barrier();
    __builtin_amdgcn_sched_barrier(0);

    #pragma unroll 1
    for (int cb = 0; cb < 16; ++cb) {
        const uint4* Bb = Bt[cb & 1];

        #pragma unroll
        for (int dh = 0; dh < 3; ++dh) {
            // substep s = cb*3+dh reads At[dh] (s mod 3 == dh), written 2 substeps ago.
            if (dh == 0 && cb < 15) XLOAD(cb + 1);

            // issue A-DMA for substep s+2 into At[(dh+2)%3]
            if (dh == 0)                    ADMA(2, cb, 2);
            else if (dh == 1) { if (cb < 15) ADMA(0, cb + 1, 0); }
            else              { if (cb < 15) ADMA(1, cb + 1, 1); }

            const uint4* Ab = At[dh];
            #pragma unroll
            for (int tl = 0; tl < 3; ++tl) {         // tap = dh*3+tl, dw = tl
                bf16x8 Af[2][2], Bf[2][2];           // [kh][oi] / [kh][wi]
                #pragma unroll
                for (int kh = 0; kh < 2; ++kh) {
                    const int arow = (tl * 4 + kh * 2 + hi) * 128 + ohalf * 64 + lo;
                    Af[kh][0] = as_bf16x8(Ab[arow]);
                    Af[kh][1] = as_bf16x8(Ab[arow + 32]);
                    const int brow = ((kh * 2 + hi) * 6 + hrow + dh) * 66 + tl + lo;
                    Bf[kh][0] = as_bf16x8(Bb[brow]);
                    Bf[kh][1] = as_bf16x8(Bb[brow + 32]);
                }
                __builtin_amdgcn_s_setprio(1);
                #pragma unroll
                for (int oi = 0; oi < 2; ++oi)
                    #pragma unroll
                    for (int wi = 0; wi < 2; ++wi)
                        #pragma unroll
                        for (int kh = 0; kh < 2; ++kh)
                            acc[oi][wi] = __builtin_amdgcn_mfma_f32_32x32x16_bf16(
                                Af[kh][oi], Bf[kh][wi], acc[oi][wi], 0, 0, 0);
                __builtin_amdgcn_s_setprio(0);
            }

            if (dh == 2 && cb < 15) FEATW((cb + 1) & 1);  // publish next-cb features

            // ---- raw barrier with counted waits ----
            // Wait target: the ADMA issued 1 substep ago (for substep s+1) must have
            // landed. N = vmem ops issued AFTER it (this substep's XLOAD + ADMA).
            if (!(cb == 15 && dh == 2)) {                // no barrier after last substep
                if (dh == 2) {
                    // newer ops: ADMA(dh2) x3; FEATW ds_writes must publish
                    asm volatile("s_waitcnt vmcnt(3) lgkmcnt(0)" ::: "memory");
                } else if (dh == 0) {
                    if (cb < 15) asm volatile("s_waitcnt vmcnt(7)" ::: "memory");
                    else         asm volatile("s_waitcnt vmcnt(3)" ::: "memory");
                } else {         // dh == 1
                    if (cb < 15) asm volatile("s_waitcnt vmcnt(3)" ::: "memory");
                    else         asm volatile("s_waitcnt vmcnt(0)" ::: "memory");
                }
                __builtin_amdgcn_s_barrier();
                __builtin_amdgcn_sched_barrier(0);
            }
        }
    }

    // ---- store: w-coalesced dword stores ----
    const int h = h0 + hrow;
    #pragma unroll
    for (int oi = 0; oi < 2; ++oi)
        #pragma unroll
        for (int wi = 0; wi < 2; ++wi) {
            const int wc = wi * 32 + lo;
            #pragma unroll
            for (int r = 0; r < 16; ++r) {
                const int o = ohalf * 64 + oi * 32 + (r & 3) + ((r >> 2) << 3) + (hi << 2);
                out[((b * OO + o) * HH + h) * WW + wc] = acc[oi][wi][r];
            }
        }
}

extern "C" void kernel_launch(void* const* d_in, const int* in_sizes, int n_in,
                              void* d_out, int out_size, void* d_ws, size_t ws_size,
                              hipStream_t stream) {
    const float* x    = (const float*)d_in[0];
    const float* beta = (const float*)d_in[1];
    const float* spl  = (const float*)d_in[2];
    const float* cf   = (const float*)d_in[3];
    float* out = (float*)d_out;
    uint4* wb  = (uint4*)d_ws;          // 73728 granules = 1.18 MB

    kan_wprep<<<288, 256, 0, stream>>>(beta, spl, cf, wb);
    kan_mfma7<<<BB * 16, 512, 0, stream>>>(x, wb, out);
}